// Round 1
// 109.787 us; speedup vs baseline: 1.0215x; 1.0215x over previous
//
#include <hip/hip_runtime.h>

typedef __bf16 bf16;
typedef __attribute__((ext_vector_type(8))) __bf16 bf16x8;
typedef __attribute__((ext_vector_type(4))) float f32x4;

// Problem constants
#define BATCH 16
#define SEQ   2048
#define CEMB  288
#define HS    32
#define NROWS (BATCH * SEQ)   // 32768

// ---------------------------------------------------------------------------
// Kernel 1: fused projections k,q,v = x @ [Wk|Wq|Wv], output bf16.
//  - Wk pre-scaled by log2(e)/sqrt(32) so attention uses exp2 directly.
//  - V written transposed: VT[b][h][t] so PV B-frags are contiguous 16B loads.
// 512 wgs x 384 threads (6 waves) x 64 rows -> 2 wgs/CU (3 waves/SIMD) for
// latency hiding (was 256 wgs x 128 rows at 1 wg/CU).
// ---------------------------------------------------------------------------
#define XSTR 296   // LDS x-tile row stride in bf16 elems (16B aligned, 2-way banks)

__global__ __launch_bounds__(384, 3) void proj_kernel(
    const float* __restrict__ x, const float* __restrict__ Wk,
    const float* __restrict__ Wq, const float* __restrict__ Wv,
    bf16* __restrict__ Kx, bf16* __restrict__ Qm, bf16* __restrict__ VT)
{
    __shared__ __align__(16) bf16 Xl[32 * XSTR];

    const int tid  = threadIdx.x;
    const int wv   = tid >> 6;
    const int lane = tid & 63;
    const int quad = lane >> 4;
    const int ln   = lane & 15;
    const int dsel = wv >> 1;    // 0=K, 1=Q, 2=V
    const int half = wv & 1;     // which 16-col half

    // log2(e) / sqrt(32)
    const float SCALE = 0.25519486439582695f;

    // Hoist the 9 B-fragments of this wave's weight n-tile (L2-hot scalar loads).
    const float* Wsrc = (dsel == 0) ? Wk : ((dsel == 1) ? Wq : Wv);
    const float mul = (dsel == 0) ? SCALE : 1.0f;
    bf16x8 wfrag[9];
    for (int kc = 0; kc < 9; ++kc) {
        bf16x8 f;
#pragma unroll
        for (int j = 0; j < 8; ++j) {
            float w = Wsrc[(kc * 32 + quad * 8 + j) * HS + half * 16 + ln];
            f[j] = (bf16)(w * mul);
        }
        wfrag[kc] = f;
    }

    const int wgRowBase = blockIdx.x * 64;
    for (int it = 0; it < 2; ++it) {
        __syncthreads();   // protect Xl reuse
        const int rb = wgRowBase + it * 32;
        // Stage 32 rows of x as bf16 into LDS (coalesced float4 reads).
#pragma unroll
        for (int i = 0; i < 6; ++i) {
            int f = tid + 384 * i;          // 0..2303  (32 rows * 72 f4/row)
            int row = f / 72;
            int c4  = f - row * 72;
            f32x4 v = ((const f32x4*)x)[(rb + row) * 72 + c4];
            bf16* d = &Xl[row * XSTR + c4 * 4];
            d[0] = (bf16)v[0]; d[1] = (bf16)v[1];
            d[2] = (bf16)v[2]; d[3] = (bf16)v[3];
        }
        __syncthreads();

#pragma unroll
        for (int m = 0; m < 2; ++m) {
            f32x4 acc = {0.f, 0.f, 0.f, 0.f};
#pragma unroll
            for (int kc = 0; kc < 9; ++kc) {
                bf16x8 a = *(const bf16x8*)&Xl[(m * 16 + ln) * XSTR + kc * 32 + quad * 8];
                acc = __builtin_amdgcn_mfma_f32_16x16x32_bf16(a, wfrag[kc], acc, 0, 0, 0);
            }
#pragma unroll
            for (int reg = 0; reg < 4; ++reg) {
                int gr = rb + m * 16 + quad * 4 + reg;   // global row in [0,32768)
                bf16 val = (bf16)acc[reg];
                if (dsel == 0) {
                    Kx[gr * HS + half * 16 + ln] = val;
                } else if (dsel == 1) {
                    Qm[gr * HS + half * 16 + ln] = val;
                } else {
                    // VT[b][h][t]
                    VT[(gr >> 11) * (HS * SEQ) + (half * 16 + ln) * SEQ + (gr & 2047)] = val;
                }
            }
        }
    }
}

// ---------------------------------------------------------------------------
// Kernel 2: fused causal attention, flash-style, NO max tracking (scores are
// O(1) by construction: sigma~1, |S| hard-bounded ~8 -> exp2 can't overflow).
//
// RESTRUCTURED vs previous version:
//  - NO LDS staging of q/vT and NO __syncthreads in the loop: the score
//    B-frag (Qm row slice) and PV B-frag (VT row slice) are already
//    contiguous 16B-per-lane loads from L2-hot global memory. Waves are
//    fully independent; waves past the diagonal break out instead of
//    idling through barriers.
//  - s-step widened 32 -> 64 (8 independent 16B loads issued per step).
//  - chunk 512 -> 256 cols: 72 (tile,chunk) units/batch x 16 = 1152 wgs
//    (4.5 wgs/CU, was 2.5), heavy-first MAP; 8 partial slots.
//  - blockIdx decode pins batch pairs to XCDs (bid%8 = b>>1) so each XCD L2
//    holds 2 batches' K/Q/VT (~768 KB) instead of all 16.
//  - P relayout C/D->A stays via wave-private LDS (proven correct).
// ---------------------------------------------------------------------------
#define PSTR 72    // P LDS row stride (bf16): 144B rows, 16B-aligned b128 reads

// 72 (tile,chunk) units per batch, heavy (full 256-col) chunks first, then
// odd-tile diagonal chunks (~3/4 weight), then even-tile diagonal (~1/4).
__constant__ unsigned char MAP_TILE[72] = {
    15,15,15,15,15,15,15,
    14,14,14,14,14,14,14,
    13,13,13,13,13,13,
    12,12,12,12,12,12,
    11,11,11,11,11,
    10,10,10,10,10,
    9,9,9,9,
    8,8,8,8,
    7,7,7,
    6,6,6,
    5,5,
    4,4,
    3,
    2,
    15,13,11,9,7,5,3,1,
    14,12,10,8,6,4,2,0 };
__constant__ unsigned char MAP_CHUNK[72] = {
    0,1,2,3,4,5,6,
    0,1,2,3,4,5,6,
    0,1,2,3,4,5,
    0,1,2,3,4,5,
    0,1,2,3,4,
    0,1,2,3,4,
    0,1,2,3,
    0,1,2,3,
    0,1,2,
    0,1,2,
    0,1,
    0,1,
    0,
    0,
    7,6,5,4,3,2,1,0,
    7,6,5,4,3,2,1,0 };

__global__ __launch_bounds__(256, 4) void attn_kernel(
    const bf16* __restrict__ Kx, const bf16* __restrict__ Qm,
    const bf16* __restrict__ VT,
    float* __restrict__ Opart, float* __restrict__ Lpart)
{
    __shared__ __align__(16) bf16 Pl[4][2][16 * PSTR];

    const int tid  = threadIdx.x;
    const int w    = tid >> 6;
    const int lane = tid & 63;
    const int quad = lane >> 4;
    const int ln   = lane & 15;

    const int bid   = blockIdx.x;
    const int u     = bid >> 4;                              // unit in [0,72)
    const int b     = ((bid & 7) << 1) | ((bid >> 3) & 1);   // batch; bid%8 = b>>1 -> XCD pin
    const int tile  = MAP_TILE[u];
    const int chunk = MAP_CHUNK[u];
    const int t0    = tile * 128;
    const int cs    = chunk * 256;
    const int ce    = min(cs + 256, t0 + 128);

    const bf16* Kb = Kx + b * SEQ * HS;
    const bf16* Qb = Qm + b * SEQ * HS;
    const bf16* Vb = VT + b * HS * SEQ;

    // K A-fragments for this wave's two 16-row subtiles (16B contiguous loads).
    int tsub[2];
    bf16x8 kfrag[2];
#pragma unroll
    for (int m = 0; m < 2; ++m) {
        tsub[m] = t0 + w * 32 + m * 16;
        kfrag[m] = *(const bf16x8*)&Kb[(tsub[m] + ln) * HS + quad * 8];
    }
    bf16x8 ones;
#pragma unroll
    for (int j = 0; j < 8; ++j) ones[j] = (bf16)1.0f;

    f32x4 Of[2][2] = {};
    f32x4 Lf[2]    = {};

    for (int s0 = cs; s0 < ce; s0 += 64) {
        if (s0 >= tsub[1] + 16) break;   // wave fully past diagonal: done

        // Direct global loads (L2-hot). Score B-frags: Q row slices.
        bf16x8 qf[4];
#pragma unroll
        for (int ss = 0; ss < 4; ++ss)
            qf[ss] = *(const bf16x8*)&Qb[(s0 + ss * 16 + ln) * HS + quad * 8];
        // PV B-frags: VT row slices. vf[h-half][s-32-block]
        bf16x8 vf[2][2];
#pragma unroll
        for (int hb = 0; hb < 2; ++hb)
#pragma unroll
            for (int kb = 0; kb < 2; ++kb)
                vf[hb][kb] = *(const bf16x8*)&Vb[(hb * 16 + ln) * SEQ + s0 + kb * 32 + quad * 8];

#pragma unroll
        for (int m = 0; m < 2; ++m) {
            if (s0 >= tsub[m] + 16) continue;        // wave-uniform: past diagonal
            const bool diagstep = (s0 + 63 > tsub[m]);
            bf16* P = &Pl[w][m][0];

            // Scores + exp2 + causal mask -> P in wave-private LDS.
#pragma unroll
            for (int ss = 0; ss < 4; ++ss) {
                if (s0 + ss * 16 > tsub[m] + 15) {
                    // 16-col block fully past diagonal for this subtile: zeros.
#pragma unroll
                    for (int reg = 0; reg < 4; ++reg)
                        P[(quad * 4 + reg) * PSTR + ss * 16 + ln] = (bf16)0.0f;
                    continue;
                }
                f32x4 z = {0.f, 0.f, 0.f, 0.f};
                f32x4 S = __builtin_amdgcn_mfma_f32_16x16x32_bf16(kfrag[m], qf[ss], z, 0, 0, 0);
#pragma unroll
                for (int reg = 0; reg < 4; ++reg) {
                    float p = __builtin_amdgcn_exp2f(S[reg]);
                    if (diagstep) {
                        int s = s0 + ss * 16 + ln;
                        int t = tsub[m] + quad * 4 + reg;
                        p = (s <= t) ? p : 0.0f;
                    }
                    P[(quad * 4 + reg) * PSTR + ss * 16 + ln] = (bf16)p;
                }
            }

            // P back as A-fragments (wave-private LDS; in-order DS per wave).
            bf16x8 ap0 = *(const bf16x8*)&P[ln * PSTR + quad * 8];
            Of[m][0] = __builtin_amdgcn_mfma_f32_16x16x32_bf16(ap0, vf[0][0], Of[m][0], 0, 0, 0);
            Of[m][1] = __builtin_amdgcn_mfma_f32_16x16x32_bf16(ap0, vf[1][0], Of[m][1], 0, 0, 0);
            Lf[m]    = __builtin_amdgcn_mfma_f32_16x16x32_bf16(ap0, ones,    Lf[m],    0, 0, 0);
            if (s0 + 32 <= tsub[m] + 15) {           // upper 32 cols live
                bf16x8 ap1 = *(const bf16x8*)&P[ln * PSTR + 32 + quad * 8];
                Of[m][0] = __builtin_amdgcn_mfma_f32_16x16x32_bf16(ap1, vf[0][1], Of[m][0], 0, 0, 0);
                Of[m][1] = __builtin_amdgcn_mfma_f32_16x16x32_bf16(ap1, vf[1][1], Of[m][1], 0, 0, 0);
                Lf[m]    = __builtin_amdgcn_mfma_f32_16x16x32_bf16(ap1, ones,    Lf[m],    0, 0, 0);
            }
        }
    }

    // Epilogue: store partial O and l for this chunk slot (plain stores; each
    // (row, slot) is owned by exactly one wave).
#pragma unroll
    for (int m = 0; m < 2; ++m) {
        if (cs >= tsub[m] + 16) continue;
#pragma unroll
        for (int reg = 0; reg < 4; ++reg) {
            int gr = b * SEQ + tsub[m] + quad * 4 + reg;
            float* od = Opart + ((size_t)chunk * NROWS + gr) * HS;
            od[ln]      = Of[m][0][reg];
            od[16 + ln] = Of[m][1][reg];
            if (ln == 0) Lpart[chunk * NROWS + gr] = Lf[m][reg];
        }
    }
}

// ---------------------------------------------------------------------------
// Kernel 3: out[gr][h] = sum_c O_c / sum_c l_c.  Slot c valid iff 256c <= t,
// which is exactly the set of written slots -> no ws memset needed.
// ---------------------------------------------------------------------------
__global__ __launch_bounds__(256) void combine_kernel(
    const float* __restrict__ Opart, const float* __restrict__ Lpart,
    float* __restrict__ out)
{
    int idx = blockIdx.x * 256 + threadIdx.x;   // float4 index, 262144 total
    int gr = idx >> 3, h4 = idx & 7;
    int t  = gr & 2047;
    int nc = (t >> 8) + 1;                       // up to 8 slots of 256 cols
    f32x4 acc = {0.f, 0.f, 0.f, 0.f};
    float l = 0.f;
    for (int c = 0; c < nc; ++c) {
        acc += ((const f32x4*)Opart)[((size_t)c * NROWS + gr) * 8 + h4];
        l   += Lpart[c * NROWS + gr];
    }
    f32x4 r = acc / l;
    ((f32x4*)out)[idx] = r;
}

// ---------------------------------------------------------------------------
// Workspace layout (bytes):
//   [0, 2M)          Kx    bf16 [32768][32]   (pre-scaled by log2e/sqrt(32))
//   [2M, 4M)         Q     bf16 [32768][32]
//   [4M, 6M)         VT    bf16 [16][32][2048]
//   [6M, 38M)        Opart f32 [8][32768][32]
//   [38M, 39M)       Lpart f32 [8][32768]
// Total ~39 MB.
// ---------------------------------------------------------------------------
extern "C" void kernel_launch(void* const* d_in, const int* in_sizes, int n_in,
                              void* d_out, int out_size, void* d_ws, size_t ws_size,
                              hipStream_t stream) {
    (void)in_sizes; (void)n_in; (void)out_size; (void)ws_size;
    const float* x  = (const float*)d_in[0];
    const float* Wk = (const float*)d_in[1];
    const float* Wq = (const float*)d_in[2];
    const float* Wv = (const float*)d_in[3];

    char* ws = (char*)d_ws;
    bf16*  Kx    = (bf16*)(ws);
    bf16*  Qm    = (bf16*)(ws + 2097152);
    bf16*  VT    = (bf16*)(ws + 4194304);
    float* Opart = (float*)(ws + 6291456);
    float* Lpart = (float*)(ws + 6291456 + 33554432);
    float* out   = (float*)d_out;

    hipLaunchKernelGGL(proj_kernel, dim3(512), dim3(384), 0, stream,
                       x, Wk, Wq, Wv, Kx, Qm, VT);
    hipLaunchKernelGGL(attn_kernel, dim3(1152), dim3(256), 0, stream,
                       Kx, Qm, VT, Opart, Lpart);
    hipLaunchKernelGGL(combine_kernel, dim3(1024), dim3(256), 0, stream,
                       Opart, Lpart, out);
}

// Round 2
// 107.680 us; speedup vs baseline: 1.0414x; 1.0196x over previous
//
#include <hip/hip_runtime.h>

typedef __bf16 bf16;
typedef __attribute__((ext_vector_type(8))) __bf16 bf16x8;
typedef __attribute__((ext_vector_type(4))) float f32x4;

// Problem constants
#define BATCH 16
#define SEQ   2048
#define CEMB  288
#define HS    32
#define NROWS (BATCH * SEQ)   // 32768

// ---------------------------------------------------------------------------
// Kernel 1: fused projections k,q,v = x @ [Wk|Wq|Wv], output bf16.
//  - Wk pre-scaled by log2(e)/sqrt(32) so attention uses exp2 directly.
//  - V written transposed: VT[b][h][t] so PV B-frags are contiguous 16B loads.
// 512 wgs x 384 threads (6 waves) x 64 rows -> 2 wgs/CU (3 waves/SIMD).
// ---------------------------------------------------------------------------
#define XSTR 296   // LDS x-tile row stride in bf16 elems (16B aligned, 2-way banks)

__global__ __launch_bounds__(384, 3) void proj_kernel(
    const float* __restrict__ x, const float* __restrict__ Wk,
    const float* __restrict__ Wq, const float* __restrict__ Wv,
    bf16* __restrict__ Kx, bf16* __restrict__ Qm, bf16* __restrict__ VT)
{
    __shared__ __align__(16) bf16 Xl[32 * XSTR];

    const int tid  = threadIdx.x;
    const int wv   = tid >> 6;
    const int lane = tid & 63;
    const int quad = lane >> 4;
    const int ln   = lane & 15;
    const int dsel = wv >> 1;    // 0=K, 1=Q, 2=V
    const int half = wv & 1;     // which 16-col half

    // log2(e) / sqrt(32)
    const float SCALE = 0.25519486439582695f;

    // Hoist the 9 B-fragments of this wave's weight n-tile (L2-hot scalar loads).
    const float* Wsrc = (dsel == 0) ? Wk : ((dsel == 1) ? Wq : Wv);
    const float mul = (dsel == 0) ? SCALE : 1.0f;
    bf16x8 wfrag[9];
    for (int kc = 0; kc < 9; ++kc) {
        bf16x8 f;
#pragma unroll
        for (int j = 0; j < 8; ++j) {
            float w = Wsrc[(kc * 32 + quad * 8 + j) * HS + half * 16 + ln];
            f[j] = (bf16)(w * mul);
        }
        wfrag[kc] = f;
    }

    const int wgRowBase = blockIdx.x * 64;
    for (int it = 0; it < 2; ++it) {
        __syncthreads();   // protect Xl reuse
        const int rb = wgRowBase + it * 32;
        // Stage 32 rows of x as bf16 into LDS (coalesced float4 reads).
#pragma unroll
        for (int i = 0; i < 6; ++i) {
            int f = tid + 384 * i;          // 0..2303  (32 rows * 72 f4/row)
            int row = f / 72;
            int c4  = f - row * 72;
            f32x4 v = ((const f32x4*)x)[(rb + row) * 72 + c4];
            bf16* d = &Xl[row * XSTR + c4 * 4];
            d[0] = (bf16)v[0]; d[1] = (bf16)v[1];
            d[2] = (bf16)v[2]; d[3] = (bf16)v[3];
        }
        __syncthreads();

#pragma unroll
        for (int m = 0; m < 2; ++m) {
            f32x4 acc = {0.f, 0.f, 0.f, 0.f};
#pragma unroll
            for (int kc = 0; kc < 9; ++kc) {
                bf16x8 a = *(const bf16x8*)&Xl[(m * 16 + ln) * XSTR + kc * 32 + quad * 8];
                acc = __builtin_amdgcn_mfma_f32_16x16x32_bf16(a, wfrag[kc], acc, 0, 0, 0);
            }
#pragma unroll
            for (int reg = 0; reg < 4; ++reg) {
                int gr = rb + m * 16 + quad * 4 + reg;   // global row in [0,32768)
                bf16 val = (bf16)acc[reg];
                if (dsel == 0) {
                    Kx[gr * HS + half * 16 + ln] = val;
                } else if (dsel == 1) {
                    Qm[gr * HS + half * 16 + ln] = val;
                } else {
                    // VT[b][h][t]
                    VT[(gr >> 11) * (HS * SEQ) + (half * 16 + ln) * SEQ + (gr & 2047)] = val;
                }
            }
        }
    }
}

// ---------------------------------------------------------------------------
// Kernel 2: fused causal attention, flash-style, NO max tracking (scores are
// O(1) by construction: sigma~1, |S| hard-bounded ~8 -> exp2 can't overflow).
//
// RESTRUCTURED (v2): the P transpose round-trip through LDS is GONE.
//  - S^T = mfma(Q-frag, K-frag): each lane's C/D values then all belong to
//    ONE t-row (t = tsub + ln), with s spread across quads.
//  - Q rows are loaded PERMUTED (lane ln takes row 8*(ln>>2)+(ln&3), and a
//    second frag at +4), so S^T's C/D layout lands each lane with exactly
//    s = {8*quad .. 8*quad+7} of its row: precisely the 16x16x32 A-fragment
//    layout for PV. Zero LDS, zero cross-lane ops, zero DS traffic.
//  - p = exp2(S) cast to bf16 directly into the PV A-frag registers.
//  - L rowsum in VALU (lane-local now) + 2 shfl_xor at epilogue; the
//    ones-MFMA rowsum is gone (saves 4 MFMAs per wave-step).
//  - chunked s-split (8 x 256-col slots), heavy-first map, XCD-pinned batch
//    pairs, direct L2-hot global loads: unchanged from v1.
// ---------------------------------------------------------------------------

// 72 (tile,chunk) units per batch, heavy (full 256-col) chunks first, then
// odd-tile diagonal chunks (~3/4 weight), then even-tile diagonal (~1/4).
__constant__ unsigned char MAP_TILE[72] = {
    15,15,15,15,15,15,15,
    14,14,14,14,14,14,14,
    13,13,13,13,13,13,
    12,12,12,12,12,12,
    11,11,11,11,11,
    10,10,10,10,10,
    9,9,9,9,
    8,8,8,8,
    7,7,7,
    6,6,6,
    5,5,
    4,4,
    3,
    2,
    15,13,11,9,7,5,3,1,
    14,12,10,8,6,4,2,0 };
__constant__ unsigned char MAP_CHUNK[72] = {
    0,1,2,3,4,5,6,
    0,1,2,3,4,5,6,
    0,1,2,3,4,5,
    0,1,2,3,4,5,
    0,1,2,3,4,
    0,1,2,3,4,
    0,1,2,3,
    0,1,2,3,
    0,1,2,
    0,1,2,
    0,1,
    0,1,
    0,
    0,
    7,6,5,4,3,2,1,0,
    7,6,5,4,3,2,1,0 };

__global__ __launch_bounds__(256, 4) void attn_kernel(
    const bf16* __restrict__ Kx, const bf16* __restrict__ Qm,
    const bf16* __restrict__ VT,
    float* __restrict__ Opart, float* __restrict__ Lpart)
{
    const int tid  = threadIdx.x;
    const int w    = tid >> 6;
    const int lane = tid & 63;
    const int quad = lane >> 4;
    const int ln   = lane & 15;

    const int bid   = blockIdx.x;
    const int u     = bid >> 4;                              // unit in [0,72)
    const int b     = ((bid & 7) << 1) | ((bid >> 3) & 1);   // batch; bid%8 = b>>1 -> XCD pin
    const int tile  = MAP_TILE[u];
    const int chunk = MAP_CHUNK[u];
    const int t0    = tile * 128;
    const int cs    = chunk * 256;
    const int ce    = min(cs + 256, t0 + 128);

    const bf16* Kb = Kx + b * SEQ * HS;
    const bf16* Qb = Qm + b * SEQ * HS;
    const bf16* Vb = VT + b * HS * SEQ;

    // K B-fragments for this wave's two 16-row subtiles (16B contiguous loads).
    int tsub[2];
    bf16x8 kfrag[2];
#pragma unroll
    for (int m = 0; m < 2; ++m) {
        tsub[m] = t0 + w * 32 + m * 16;
        kfrag[m] = *(const bf16x8*)&Kb[(tsub[m] + ln) * HS + quad * 8];
    }

    // Permuted Q-row offset: A-frag row ln <-> s-offset 8*(ln>>2)+(ln&3).
    const int qrow = 8 * (ln >> 2) + (ln & 3);
    const int t_row = ln;   // this lane's t-row (local) for all S^T outputs

    f32x4 Of[2][2] = {};
    float Lacc[2]  = {0.f, 0.f};

    for (int s0 = cs; s0 < ce; s0 += 64) {
        if (s0 >= tsub[1] + 16) break;   // wave fully past diagonal: done

        // Direct global loads (L2-hot). Permuted Q A-frags: two per 32-chunk.
        bf16x8 qfA[2], qfB[2];
#pragma unroll
        for (int c = 0; c < 2; ++c) {
            qfA[c] = *(const bf16x8*)&Qb[(s0 + 32 * c + qrow) * HS + quad * 8];
            qfB[c] = *(const bf16x8*)&Qb[(s0 + 32 * c + qrow + 4) * HS + quad * 8];
        }
        // PV B-frags: VT row slices. vf[h-half][s-32-chunk]
        bf16x8 vf[2][2];
#pragma unroll
        for (int hb = 0; hb < 2; ++hb)
#pragma unroll
            for (int c = 0; c < 2; ++c)
                vf[hb][c] = *(const bf16x8*)&Vb[(hb * 16 + ln) * SEQ + s0 + c * 32 + quad * 8];

#pragma unroll
        for (int m = 0; m < 2; ++m) {
            const int t = tsub[m] + t_row;
#pragma unroll
            for (int c = 0; c < 2; ++c) {
                const int sb = s0 + 32 * c;
                if (sb >= tsub[m] + 16) continue;      // wave-uniform: chunk dead
                const bool diag = (sb + 31 > tsub[m]);

                // S^T: rows = permuted s, cols = t.  K=HS=32 exact.
                f32x4 z = {0.f, 0.f, 0.f, 0.f};
                f32x4 SA = __builtin_amdgcn_mfma_f32_16x16x32_bf16(qfA[c], kfrag[m], z, 0, 0, 0);
                f32x4 SB = __builtin_amdgcn_mfma_f32_16x16x32_bf16(qfB[c], kfrag[m], z, 0, 0, 0);

                // p = exp2(S) (log2e folded into K), causal mask, lane-local L.
                const int sAb = sb + 8 * quad;
                float pA[4], pB[4];
#pragma unroll
                for (int r = 0; r < 4; ++r) {
                    pA[r] = __builtin_amdgcn_exp2f(SA[r]);
                    pB[r] = __builtin_amdgcn_exp2f(SB[r]);
                    if (diag) {
                        pA[r] = (sAb + r     <= t) ? pA[r] : 0.0f;
                        pB[r] = (sAb + r + 4 <= t) ? pB[r] : 0.0f;
                    }
                    Lacc[m] += pA[r] + pB[r];
                }

                // Pack straight into the PV A-fragment (no cross-lane moves).
                bf16x8 ap;
#pragma unroll
                for (int r = 0; r < 4; ++r) {
                    ap[r]     = (bf16)pA[r];
                    ap[r + 4] = (bf16)pB[r];
                }

                Of[m][0] = __builtin_amdgcn_mfma_f32_16x16x32_bf16(ap, vf[0][c], Of[m][0], 0, 0, 0);
                Of[m][1] = __builtin_amdgcn_mfma_f32_16x16x32_bf16(ap, vf[1][c], Of[m][1], 0, 0, 0);
            }
        }
    }

    // Epilogue: store partial O and l for this chunk slot (plain stores; each
    // (row, slot) is owned by exactly one wave).
#pragma unroll
    for (int m = 0; m < 2; ++m) {
        if (cs >= tsub[m] + 16) continue;
#pragma unroll
        for (int reg = 0; reg < 4; ++reg) {
            int gr = b * SEQ + tsub[m] + quad * 4 + reg;
            float* od = Opart + ((size_t)chunk * NROWS + gr) * HS;
            od[ln]      = Of[m][0][reg];
            od[16 + ln] = Of[m][1][reg];
        }
        // L: lane-local partials -> reduce across the 4 quads (same t-row).
        float l = Lacc[m];
        l += __shfl_xor(l, 16, 64);
        l += __shfl_xor(l, 32, 64);
        if (quad == 0)
            Lpart[chunk * NROWS + b * SEQ + tsub[m] + ln] = l;
    }
}

// ---------------------------------------------------------------------------
// Kernel 3: out[gr][h] = sum_c O_c / sum_c l_c.  Slot c valid iff 256c <= t,
// which is exactly the set of written slots -> no ws memset needed.
// ---------------------------------------------------------------------------
__global__ __launch_bounds__(256) void combine_kernel(
    const float* __restrict__ Opart, const float* __restrict__ Lpart,
    float* __restrict__ out)
{
    int idx = blockIdx.x * 256 + threadIdx.x;   // float4 index, 262144 total
    int gr = idx >> 3, h4 = idx & 7;
    int t  = gr & 2047;
    int nc = (t >> 8) + 1;                       // up to 8 slots of 256 cols
    f32x4 acc = {0.f, 0.f, 0.f, 0.f};
    float l = 0.f;
    for (int c = 0; c < nc; ++c) {
        acc += ((const f32x4*)Opart)[((size_t)c * NROWS + gr) * 8 + h4];
        l   += Lpart[c * NROWS + gr];
    }
    f32x4 r = acc / l;
    ((f32x4*)out)[idx] = r;
}

// ---------------------------------------------------------------------------
// Workspace layout (bytes):
//   [0, 2M)          Kx    bf16 [32768][32]   (pre-scaled by log2e/sqrt(32))
//   [2M, 4M)         Q     bf16 [32768][32]
//   [4M, 6M)         VT    bf16 [16][32][2048]
//   [6M, 38M)        Opart f32 [8][32768][32]
//   [38M, 39M)       Lpart f32 [8][32768]
// Total ~39 MB.
// ---------------------------------------------------------------------------
extern "C" void kernel_launch(void* const* d_in, const int* in_sizes, int n_in,
                              void* d_out, int out_size, void* d_ws, size_t ws_size,
                              hipStream_t stream) {
    (void)in_sizes; (void)n_in; (void)out_size; (void)ws_size;
    const float* x  = (const float*)d_in[0];
    const float* Wk = (const float*)d_in[1];
    const float* Wq = (const float*)d_in[2];
    const float* Wv = (const float*)d_in[3];

    char* ws = (char*)d_ws;
    bf16*  Kx    = (bf16*)(ws);
    bf16*  Qm    = (bf16*)(ws + 2097152);
    bf16*  VT    = (bf16*)(ws + 4194304);
    float* Opart = (float*)(ws + 6291456);
    float* Lpart = (float*)(ws + 6291456 + 33554432);
    float* out   = (float*)d_out;

    hipLaunchKernelGGL(proj_kernel, dim3(512), dim3(384), 0, stream,
                       x, Wk, Wq, Wv, Kx, Qm, VT);
    hipLaunchKernelGGL(attn_kernel, dim3(1152), dim3(256), 0, stream,
                       Kx, Qm, VT, Opart, Lpart);
    hipLaunchKernelGGL(combine_kernel, dim3(1024), dim3(256), 0, stream,
                       Opart, Lpart, out);
}

// Round 3
// 105.107 us; speedup vs baseline: 1.0669x; 1.0245x over previous
//
#include <hip/hip_runtime.h>

typedef __bf16 bf16;
typedef __attribute__((ext_vector_type(8))) __bf16 bf16x8;
typedef __attribute__((ext_vector_type(4))) float f32x4;

// Problem constants
#define BATCH 16
#define SEQ   2048
#define CEMB  288
#define HS    32
#define NROWS (BATCH * SEQ)   // 32768

// ---------------------------------------------------------------------------
// Kernel 1: fused projections k,q,v = x @ [Wk|Wq|Wv], output bf16.
//  - Wk pre-scaled by log2(e)/sqrt(32) so attention uses exp2 directly.
//  - V written transposed: VT[b][h][t] so PV B-frags are contiguous 16B loads.
// 512 wgs x 384 threads (6 waves) x 64 rows -> 2 wgs/CU (3 waves/SIMD).
// HBM floor: 37.75 MB x read + 6 MB writes ~= 7 us.
// ---------------------------------------------------------------------------
#define XSTR 296   // LDS x-tile row stride in bf16 elems (16B aligned, 2-way banks)

__global__ __launch_bounds__(384, 3) void proj_kernel(
    const float* __restrict__ x, const float* __restrict__ Wk,
    const float* __restrict__ Wq, const float* __restrict__ Wv,
    bf16* __restrict__ Kx, bf16* __restrict__ Qm, bf16* __restrict__ VT)
{
    __shared__ __align__(16) bf16 Xl[32 * XSTR];

    const int tid  = threadIdx.x;
    const int wv   = tid >> 6;
    const int lane = tid & 63;
    const int quad = lane >> 4;
    const int ln   = lane & 15;
    const int dsel = wv >> 1;    // 0=K, 1=Q, 2=V
    const int half = wv & 1;     // which 16-col half

    // log2(e) / sqrt(32)
    const float SCALE = 0.25519486439582695f;

    // Hoist the 9 B-fragments of this wave's weight n-tile (L2-hot scalar loads).
    const float* Wsrc = (dsel == 0) ? Wk : ((dsel == 1) ? Wq : Wv);
    const float mul = (dsel == 0) ? SCALE : 1.0f;
    bf16x8 wfrag[9];
    for (int kc = 0; kc < 9; ++kc) {
        bf16x8 f;
#pragma unroll
        for (int j = 0; j < 8; ++j) {
            float w = Wsrc[(kc * 32 + quad * 8 + j) * HS + half * 16 + ln];
            f[j] = (bf16)(w * mul);
        }
        wfrag[kc] = f;
    }

    const int wgRowBase = blockIdx.x * 64;
    for (int it = 0; it < 2; ++it) {
        __syncthreads();   // protect Xl reuse
        const int rb = wgRowBase + it * 32;
        // Stage 32 rows of x as bf16 into LDS (coalesced float4 reads).
#pragma unroll
        for (int i = 0; i < 6; ++i) {
            int f = tid + 384 * i;          // 0..2303  (32 rows * 72 f4/row)
            int row = f / 72;
            int c4  = f - row * 72;
            f32x4 v = ((const f32x4*)x)[(rb + row) * 72 + c4];
            bf16* d = &Xl[row * XSTR + c4 * 4];
            d[0] = (bf16)v[0]; d[1] = (bf16)v[1];
            d[2] = (bf16)v[2]; d[3] = (bf16)v[3];
        }
        __syncthreads();

#pragma unroll
        for (int m = 0; m < 2; ++m) {
            f32x4 acc = {0.f, 0.f, 0.f, 0.f};
#pragma unroll
            for (int kc = 0; kc < 9; ++kc) {
                bf16x8 a = *(const bf16x8*)&Xl[(m * 16 + ln) * XSTR + kc * 32 + quad * 8];
                acc = __builtin_amdgcn_mfma_f32_16x16x32_bf16(a, wfrag[kc], acc, 0, 0, 0);
            }
#pragma unroll
            for (int reg = 0; reg < 4; ++reg) {
                int gr = rb + m * 16 + quad * 4 + reg;   // global row in [0,32768)
                bf16 val = (bf16)acc[reg];
                if (dsel == 0) {
                    Kx[gr * HS + half * 16 + ln] = val;
                } else if (dsel == 1) {
                    Qm[gr * HS + half * 16 + ln] = val;
                } else {
                    // VT[b][h][t]
                    VT[(gr >> 11) * (HS * SEQ) + (half * 16 + ln) * SEQ + (gr & 2047)] = val;
                }
            }
        }
    }
}

// ---------------------------------------------------------------------------
// Kernel 2: fused causal attention, flash-style, NO max tracking (scores are
// O(1) by construction: sigma~1, |S| hard-bounded ~8 -> exp2 can't overflow).
//
// v3 = v2 structure (transpose-free S^T + permuted-Q A-frag trick, zero LDS,
// direct L2-hot global loads, XCD-pinned batch pairs) with two changes:
//  - L rowsum moved BACK to the ones-B MFMA (v1-proven): deletes 32 VALU adds
//    + 2 shfl per 64-step from the VALU-bound inner loop; the 4 extra MFMAs
//    ride the half-idle matrix pipe. L = sum(bf16(p)) matches the numerator
//    rounding.
//  - chunking 8x256 -> 4x512 (round-0-proven map + combine): Opart traffic
//    18.9 -> 10.5 MB each way, ~-2.7 us HBM. Grid 640 wgs (2.5/CU).
// ---------------------------------------------------------------------------

// 40 (tile,chunk) units per batch, heavy (full 512-col) chunks first, then
// diagonal chunks in decreasing-weight order.
__constant__ unsigned char MAP_TILE[40] = {
    4,5,6,7, 8,8,9,9, 10,10,11,11, 12,12,12, 13,13,13, 14,14,14, 15,15,15,
    3,7,11,15, 2,6,10,14, 1,5,9,13, 0,4,8,12 };
__constant__ unsigned char MAP_CHUNK[40] = {
    0,0,0,0, 0,1,0,1, 0,1,0,1, 0,1,2, 0,1,2, 0,1,2, 0,1,2,
    0,1,2,3, 0,1,2,3, 0,1,2,3, 0,1,2,3 };

__global__ __launch_bounds__(256, 4) void attn_kernel(
    const bf16* __restrict__ Kx, const bf16* __restrict__ Qm,
    const bf16* __restrict__ VT,
    float* __restrict__ Opart, float* __restrict__ Lpart)
{
    const int tid  = threadIdx.x;
    const int w    = tid >> 6;
    const int lane = tid & 63;
    const int quad = lane >> 4;
    const int ln   = lane & 15;

    const int bid   = blockIdx.x;
    const int u     = bid >> 4;                              // unit in [0,40)
    const int b     = ((bid & 7) << 1) | ((bid >> 3) & 1);   // batch; bid%8 = b>>1 -> XCD pin
    const int tile  = MAP_TILE[u];
    const int chunk = MAP_CHUNK[u];
    const int t0    = tile * 128;
    const int cs    = chunk * 512;
    const int ce    = min(cs + 512, t0 + 128);

    const bf16* Kb = Kx + b * SEQ * HS;
    const bf16* Qb = Qm + b * SEQ * HS;
    const bf16* Vb = VT + b * HS * SEQ;

    // K B-fragments for this wave's two 16-row subtiles (16B contiguous loads).
    int tsub[2];
    bf16x8 kfrag[2];
#pragma unroll
    for (int m = 0; m < 2; ++m) {
        tsub[m] = t0 + w * 32 + m * 16;
        kfrag[m] = *(const bf16x8*)&Kb[(tsub[m] + ln) * HS + quad * 8];
    }
    bf16x8 ones;
#pragma unroll
    for (int j = 0; j < 8; ++j) ones[j] = (bf16)1.0f;

    // Permuted Q-row offset: A-frag row ln <-> s-offset 8*(ln>>2)+(ln&3).
    const int qrow = 8 * (ln >> 2) + (ln & 3);
    const int t_row = ln;   // this lane's t-row (local) for all S^T outputs

    f32x4 Of[2][2] = {};
    f32x4 Lf[2]    = {};

    for (int s0 = cs; s0 < ce; s0 += 64) {
        if (s0 >= tsub[1] + 16) break;   // wave fully past diagonal: done

        // Direct global loads (L2-hot). Permuted Q A-frags: two per 32-chunk.
        bf16x8 qfA[2], qfB[2];
#pragma unroll
        for (int c = 0; c < 2; ++c) {
            qfA[c] = *(const bf16x8*)&Qb[(s0 + 32 * c + qrow) * HS + quad * 8];
            qfB[c] = *(const bf16x8*)&Qb[(s0 + 32 * c + qrow + 4) * HS + quad * 8];
        }
        // PV B-frags: VT row slices. vf[h-half][s-32-chunk]
        bf16x8 vf[2][2];
#pragma unroll
        for (int hb = 0; hb < 2; ++hb)
#pragma unroll
            for (int c = 0; c < 2; ++c)
                vf[hb][c] = *(const bf16x8*)&Vb[(hb * 16 + ln) * SEQ + s0 + c * 32 + quad * 8];

#pragma unroll
        for (int m = 0; m < 2; ++m) {
            const int t = tsub[m] + t_row;
#pragma unroll
            for (int c = 0; c < 2; ++c) {
                const int sb = s0 + 32 * c;
                if (sb >= tsub[m] + 16) continue;      // wave-uniform: chunk dead
                const bool diag = (sb + 31 > tsub[m]);

                // S^T: rows = permuted s, cols = t.  K=HS=32 exact.
                f32x4 z = {0.f, 0.f, 0.f, 0.f};
                f32x4 SA = __builtin_amdgcn_mfma_f32_16x16x32_bf16(qfA[c], kfrag[m], z, 0, 0, 0);
                f32x4 SB = __builtin_amdgcn_mfma_f32_16x16x32_bf16(qfB[c], kfrag[m], z, 0, 0, 0);

                // p = exp2(S) (log2e folded into K), causal mask.
                const int sAb = sb + 8 * quad;
                float pA[4], pB[4];
#pragma unroll
                for (int r = 0; r < 4; ++r) {
                    pA[r] = __builtin_amdgcn_exp2f(SA[r]);
                    pB[r] = __builtin_amdgcn_exp2f(SB[r]);
                    if (diag) {
                        pA[r] = (sAb + r     <= t) ? pA[r] : 0.0f;
                        pB[r] = (sAb + r + 4 <= t) ? pB[r] : 0.0f;
                    }
                }

                // Pack straight into the PV A-fragment (no cross-lane moves).
                bf16x8 ap;
#pragma unroll
                for (int r = 0; r < 4; ++r) {
                    ap[r]     = (bf16)pA[r];
                    ap[r + 4] = (bf16)pB[r];
                }

                Of[m][0] = __builtin_amdgcn_mfma_f32_16x16x32_bf16(ap, vf[0][c], Of[m][0], 0, 0, 0);
                Of[m][1] = __builtin_amdgcn_mfma_f32_16x16x32_bf16(ap, vf[1][c], Of[m][1], 0, 0, 0);
                Lf[m]    = __builtin_amdgcn_mfma_f32_16x16x32_bf16(ap, ones,    Lf[m],    0, 0, 0);
            }
        }
    }

    // Epilogue: store partial O and l for this chunk slot (plain stores; each
    // (row, slot) is owned by exactly one wave).  Lf C/D rows = t-local
    // quad*4+reg, all cols equal (ones-B) -> store from ln==0.
#pragma unroll
    for (int m = 0; m < 2; ++m) {
        if (cs >= tsub[m] + 16) continue;
#pragma unroll
        for (int reg = 0; reg < 4; ++reg) {
            int gr = b * SEQ + tsub[m] + quad * 4 + reg;
            float* od = Opart + ((size_t)chunk * NROWS + gr) * HS;
            od[ln]      = Of[m][0][reg];
            od[16 + ln] = Of[m][1][reg];
            if (ln == 0) Lpart[chunk * NROWS + gr] = Lf[m][reg];
        }
    }
}

// ---------------------------------------------------------------------------
// Kernel 3: out[gr][h] = sum_c O_c / sum_c l_c.  Slot c valid iff 512c <= t,
// which is exactly the set of written slots -> no ws memset needed.
// ---------------------------------------------------------------------------
__global__ __launch_bounds__(256) void combine_kernel(
    const float* __restrict__ Opart, const float* __restrict__ Lpart,
    float* __restrict__ out)
{
    int idx = blockIdx.x * 256 + threadIdx.x;   // float4 index, 262144 total
    int gr = idx >> 3, h4 = idx & 7;
    int t  = gr & 2047;
    int nc = (t >> 9) + 1;                       // up to 4 slots of 512 cols
    f32x4 acc = {0.f, 0.f, 0.f, 0.f};
    float l = 0.f;
    for (int c = 0; c < nc; ++c) {
        acc += ((const f32x4*)Opart)[((size_t)c * NROWS + gr) * 8 + h4];
        l   += Lpart[c * NROWS + gr];
    }
    f32x4 r = acc / l;
    ((f32x4*)out)[idx] = r;
}

// ---------------------------------------------------------------------------
// Workspace layout (bytes):
//   [0, 2M)          Kx    bf16 [32768][32]   (pre-scaled by log2e/sqrt(32))
//   [2M, 4M)         Q     bf16 [32768][32]
//   [4M, 6M)         VT    bf16 [16][32][2048]
//   [6M, 22M)        Opart f32 [4][32768][32]
//   [22M, 22.5M)     Lpart f32 [4][32768]
// Total ~22.5 MB.
// ---------------------------------------------------------------------------
extern "C" void kernel_launch(void* const* d_in, const int* in_sizes, int n_in,
                              void* d_out, int out_size, void* d_ws, size_t ws_size,
                              hipStream_t stream) {
    (void)in_sizes; (void)n_in; (void)out_size; (void)ws_size;
    const float* x  = (const float*)d_in[0];
    const float* Wk = (const float*)d_in[1];
    const float* Wq = (const float*)d_in[2];
    const float* Wv = (const float*)d_in[3];

    char* ws = (char*)d_ws;
    bf16*  Kx    = (bf16*)(ws);
    bf16*  Qm    = (bf16*)(ws + 2097152);
    bf16*  VT    = (bf16*)(ws + 4194304);
    float* Opart = (float*)(ws + 6291456);
    float* Lpart = (float*)(ws + 6291456 + 16777216);
    float* out   = (float*)d_out;

    hipLaunchKernelGGL(proj_kernel, dim3(512), dim3(384), 0, stream,
                       x, Wk, Wq, Wv, Kx, Qm, VT);
    hipLaunchKernelGGL(attn_kernel, dim3(640), dim3(256), 0, stream,
                       Kx, Qm, VT, Opart, Lpart);
    hipLaunchKernelGGL(combine_kernel, dim3(1024), dim3(256), 0, stream,
                       Opart, Lpart, out);
}